// Round 18
// baseline (436.398 us; speedup 1.0000x reference)
//
#include <hip/hip_runtime.h>
#include <stdint.h>

typedef __attribute__((ext_vector_type(4))) float f32x4;
typedef __attribute__((ext_vector_type(8))) __bf16 bf16x8;
typedef __attribute__((ext_vector_type(4))) __bf16 bf16x4;

#define NB 2
#define NS 2048
#define ND 2048
#define NH 16
#define NHD 128
#define NM (NB*NS)      // 4096 rows
#define NQKV (3*ND)     // 6144

__device__ __forceinline__ short f2bf(float f) {
  union { float f; uint32_t u; } c; c.f = f;
  uint32_t r = (c.u + 0x7FFFu + ((c.u >> 16) & 1u)) >> 16;
  return (short)r;
}

__device__ __forceinline__ void gl_lds16(const short* g, short* l) {
  __builtin_amdgcn_global_load_lds(
      (const __attribute__((address_space(1))) void*)g,
      (__attribute__((address_space(3))) void*)l, 16, 0, 0);
}

// ---------------- fused prepass: cvt hidden + transpose W_qkv + transpose W_o ----
__global__ __launch_bounds__(256) void prep_kernel(
    const float* __restrict__ hidden, short* __restrict__ Abuf,
    const float* __restrict__ W_qkv, short* __restrict__ WqkvT,
    const float* __restrict__ W_o, short* __restrict__ WoT) {
  __shared__ float tile[64][65];
  const int b = blockIdx.x;
  if (b < 8192) {
    const int i = b * 256 + threadIdx.x;
    float4 v = ((const float4*)hidden)[i];
    short4 o;
    o.x = f2bf(v.x); o.y = f2bf(v.y); o.z = f2bf(v.z); o.w = f2bf(v.w);
    ((short4*)Abuf)[i] = o;
  } else {
    const float* in; short* out; int cols, t;
    if (b < 11264) { in = W_qkv; out = WqkvT; cols = NQKV; t = b - 8192; }
    else           { in = W_o;   out = WoT;   cols = ND;   t = b - 11264; }
    const int rows = ND;
    const int nbx = cols >> 6;
    const int bx = t % nbx, by = t / nbx;
    const int tx = threadIdx.x & 63, ty = threadIdx.x >> 6;
    const int r0 = by * 64, c0 = bx * 64;
    for (int i = ty; i < 64; i += 4)
      tile[i][tx] = in[(size_t)(r0 + i) * cols + c0 + tx];
    __syncthreads();
    for (int i = ty; i < 64; i += 4)
      out[(size_t)(c0 + i) * rows + r0 + tx] = f2bf(tile[tx][i]);
  }
}

// ---------------- bf16 GEMM, 128x128, BK=64, 4 waves (2x2), 2 blocks/CU ----------------
// r17: B fragments read DIRECTLY from global (L2-resident per-XCD panel via the
// 2D XCD chunking) — LDS holds only A (dbuf 32 KB). Rationale: calibrated model
// shows the kernel is LDS-read-throughput-bound (~14 cy/b128/CU: 256 reads/step
// = 3584 cy -> 143 us predicted, 145-147 measured). Halving LDS reads moves B
// traffic to the un-contended VMEM/L2 path. B values identical -> bitwise-same
// output (absmax must stay 0.03125).
// Sync invariants kept from r16: lgkmcnt(0) before EVERY barrier (cross-wave
// LDS-read vs DMA-write hazard); counted vmcnt at P0-end: outstanding there is
// exactly {A(t+2):4 if staged, bfHi(t):4} (bf loads are compiler-waited before
// their MMA use), so vmcnt(8)/vmcnt(4) retires A(t+1) by FIFO order.
template<int EPI>
__global__ __launch_bounds__(256, 2) void gemm_kernel(
    const short* __restrict__ A, const short* __restrict__ Bt, int K, int N, int nbx,
    const float* __restrict__ bias,
    short* __restrict__ Qb, short* __restrict__ Kb, short* __restrict__ Vtb,
    const float* __restrict__ residual, float* __restrict__ out) {
  const int tid = threadIdx.x;
  const int wid = tid >> 6, l = tid & 63;
  const int l15 = l & 15, l4 = l >> 4;
  const int wr = wid >> 1, wc = wid & 1;

  // 2D XCD chunking: xcd = flat & 7; by fastest -> per-XCD B slice L2-resident
  const int flat = blockIdx.x;
  const int xcd = flat & 7;
  const int j = flat >> 3;
  const int nchunk = nbx >> 3;
  const int bx = nchunk * xcd + (j >> 5);
  const int by = j & 31;                      // NM/128 = 32 row-panels
  const int rowBase = by * 128, colBase = bx * 128;

  __shared__ short As[2][128 * 64];   // 32 KB total (A only)

  f32x4 acc[4][4] = {};
  const int nk = K >> 6;

  const int crow = tid >> 3;
  const int scol = ((tid & 7) ^ ((tid >> 3) & 7)) << 3;

#define STGC(buf, ci, kt0)                                                       \
    gl_lds16(A + (size_t)(rowBase + (ci) * 32 + crow) * K +                      \
                 (size_t)(kt0) * 64 + scol,                                      \
             &As[buf][((ci) * 32 + wid * 8) * 64])
#define STG_A(buf, kt0) do { STGC(buf, 0, kt0); STGC(buf, 1, kt0);               \
    STGC(buf, 2, kt0); STGC(buf, 3, kt0); } while (0)

  bf16x8 afS0[4][2], afS1[4][2], bfLo[2][2], bfHi[2][2];
  const int aXor = (l15 & 7) << 4;
  const int aColB = l4 * 16;

#define LDA(buf, DST)                                                            \
  _Pragma("unroll")                                                              \
  for (int m_ = 0; m_ < 4; ++m_) {                                               \
    const int r_ = wr * 64 + m_ * 16 + l15;                                      \
    _Pragma("unroll")                                                            \
    for (int kk_ = 0; kk_ < 2; ++kk_)                                            \
      DST[m_][kk_] = *(const bf16x8*)((const char*)&As[buf][0] + r_ * 128 +      \
                                      ((kk_ * 64 + aColB) ^ aXor));              \
  }
// B fragment straight from global: row = colBase + wc*64 + (nb+n)*16 + l15,
// elems kt*64 + kk*32 + l4*8 (no swizzle — L2 path, not LDS banks)
#define LDBG(DST, nb, kt0)                                                       \
  _Pragma("unroll")                                                              \
  for (int n_ = 0; n_ < 2; ++n_) {                                               \
    const size_t r_ = (size_t)(colBase + wc * 64 + ((nb) + n_) * 16 + l15);      \
    _Pragma("unroll")                                                            \
    for (int kk_ = 0; kk_ < 2; ++kk_)                                            \
      DST[n_][kk_] = *(const bf16x8*)(Bt + r_ * K + (kt0) * 64 + kk_ * 32 + l4 * 8); \
  }
#define MMAQ(AF, BF, nb)                                                         \
  _Pragma("unroll")                                                              \
  for (int m_ = 0; m_ < 4; ++m_)                                                 \
    _Pragma("unroll")                                                            \
    for (int n_ = 0; n_ < 2; ++n_)                                               \
      _Pragma("unroll")                                                          \
      for (int kk_ = 0; kk_ < 2; ++kk_)                                          \
        acc[m_][(nb) + n_] = __builtin_amdgcn_mfma_f32_16x16x32_bf16(            \
            AF[m_][kk_], BF[n_][kk_], acc[m_][(nb) + n_], 0, 0, 0);

  // P0: stage A(t+2) into As[cur] (safe: all LDS reads drained at entry barrier);
  //     load bfHi(t) from global; MMA half0 (bfLo(t), loaded last P1);
  //     lgkm(0); vmcnt(stA?8:4) -> A(t+1) retired; barrier.
  // P1: LDA(t+1) from other buf + load bfLo(t+1) global; MMA half1 (bfHi);
  //     lgkm(0); barrier.
#define TILE(kt, AFc, AFn, cur)                                                  \
  do {                                                                           \
    const bool stA = (kt) + 2 < nk;                                              \
    const bool nxt = (kt) + 1 < nk;                                              \
    if (stA) STG_A(cur, (kt) + 2);                                               \
    LDBG(bfHi, 2, (kt));                                                         \
    __builtin_amdgcn_sched_barrier(0);                                           \
    __builtin_amdgcn_s_setprio(1);                                               \
    MMAQ(AFc, bfLo, 0);                                                          \
    __builtin_amdgcn_s_setprio(0);                                               \
    __builtin_amdgcn_sched_barrier(0);                                           \
    asm volatile("s_waitcnt lgkmcnt(0)" ::: "memory");                           \
    if (stA) { asm volatile("s_waitcnt vmcnt(8)" ::: "memory"); }                \
    else     { asm volatile("s_waitcnt vmcnt(4)" ::: "memory"); }                \
    __builtin_amdgcn_s_barrier();                                                \
    if (nxt) { LDA(cur ^ 1, AFn); LDBG(bfLo, 0, (kt) + 1); }                     \
    __builtin_amdgcn_sched_barrier(0);                                           \
    __builtin_amdgcn_s_setprio(1);                                               \
    MMAQ(AFc, bfHi, 2);                                                          \
    __builtin_amdgcn_s_setprio(0);                                               \
    __builtin_amdgcn_sched_barrier(0);                                           \
    asm volatile("s_waitcnt lgkmcnt(0)" ::: "memory");                           \
    __builtin_amdgcn_s_barrier();                                                \
  } while (0)

  // prologue: A(0),A(1) DMA; vmcnt(4) -> A(0) landed (A(1) flying); barrier;
  // fragment reads for tile 0 + bfLo(0); drain + barrier (TILE(0) stages As[0]).
  STG_A(0, 0);
  STG_A(1, 1);
  asm volatile("s_waitcnt vmcnt(4)" ::: "memory");
  __builtin_amdgcn_s_barrier();
  LDA(0, afS0); LDBG(bfLo, 0, 0);
  asm volatile("s_waitcnt lgkmcnt(0)" ::: "memory");
  __builtin_amdgcn_s_barrier();

  for (int kt = 0; kt < nk; kt += 2) {
    TILE(kt,     afS0, afS1, 0);
    TILE(kt + 1, afS1, afS0, 1);
  }
#undef STGC
#undef STG_A
#undef LDA
#undef LDBG
#undef MMAQ
#undef TILE

#pragma unroll
  for (int m = 0; m < 4; ++m) {
#pragma unroll
    for (int n = 0; n < 4; ++n) {
#pragma unroll
      for (int r = 0; r < 4; ++r) {
        const int row = rowBase + wr * 64 + m * 16 + l4 * 4 + r;
        const int col = colBase + wc * 64 + n * 16 + l15;
        float v = acc[m][n][r] + bias[col];
        if (EPI == 0) {
          const int h = col / 384;
          const int sub = col - h * 384;
          const int t = sub >> 7, hd = sub & 127;
          const int bb = row >> 11, s = row & 2047;
          const size_t bh = (size_t)bb * NH + h;
          if (t == 0)      Qb[(bh * NS + s) * NHD + hd] = f2bf(v * 0.08838834764831845f);
          else if (t == 1) Kb[(bh * NS + s) * NHD + hd] = f2bf(v);
          else             Vtb[(bh * NHD + hd) * NS + s] = f2bf(v);
        } else {
          const size_t idx = (size_t)row * N + col;
          out[idx] = v + residual[idx];
        }
      }
    }
  }
}

// ---------------- flash attention (r11/r16 known-good, byte-identical) ----------------
__global__ __launch_bounds__(256, 2) void attn_kernel(
    const short* __restrict__ Qb, const short* __restrict__ Kb,
    const short* __restrict__ Vtb, const float* __restrict__ alibi,
    const int* __restrict__ amask, short* __restrict__ Ob) {
  const int tid = threadIdx.x;
  const int w = tid >> 6, l = tid & 63;
  const int l15 = l & 15, l4 = l >> 4;
  const int flat = blockIdx.x;
  const int bh = flat & 31;
  const int y = (flat >> 5) & 7, z = flat >> 8;
  const int qt = z ? (15 - y) : y;
  const int bb = bh >> 4, h = bh & 15;
  const int q0 = qt * 128;
  const int qw = q0 + w * 32;
  const int NT = 2 * qt + 2;

  __shared__ float biasLds[NS];
  __shared__ short Ks[2][64 * 128];
  __shared__ short Plds[4][32 * 64];

  {
    const float* abase = alibi + (size_t)bh * NS;
    const int* mbase = amask + (size_t)bb * NS;
    for (int i = tid; i < NS; i += 256)
      biasLds[i] = mbase[i] ? abase[i] : -1e30f;
  }

  const short* kbase = Kb + (size_t)bh * NS * NHD;
  const short* vbase = Vtb + (size_t)bh * NHD * NS;

#define KSTAGE(buf, kt0) do {                                                  \
    _Pragma("unroll")                                                          \
    for (int i_ = 0; i_ < 4; ++i_) {                                           \
      const int Lb_ = w * 4096 + i_ * 1024 + l * 16;                           \
      const int row_ = Lb_ >> 8;                                               \
      const int X_ = (Lb_ & 255) ^ ((row_ & 7) << 4);                          \
      gl_lds16((const short*)((const char*)kbase + (size_t)((kt0) * 64 + row_) * 256 + X_), \
               (short*)((char*)&Ks[buf][0] + (w * 4096 + i_ * 1024)));         \
    }                                                                          \
  } while (0)

  const short* qp = Qb + ((size_t)bh * NS + qw + l15) * NHD + l4 * 8;
  bf16x8 qf[2][4];
#pragma unroll
  for (int c = 0; c < 2; ++c)
#pragma unroll
    for (int s = 0; s < 4; ++s)
      qf[c][s] = *(const bf16x8*)(qp + c * 16 * NHD + s * 32);

  f32x4 acc[2][8] = {};
  float mrun[2] = {-1e30f, -1e30f}, lrun[2] = {0.f, 0.f};

  short* myP = &Plds[w][0];
  const int pswzB = (l15 & 7) << 4;
  const int qg0 = qw + l15, qg1 = qw + 16 + l15;

  KSTAGE(0, 0);
  __syncthreads();
  int cur = 0;

  for (int t = 0; t < NT; ++t) {
    const int k0 = t << 6;
    if (t + 1 < NT) KSTAGE(cur ^ 1, t + 1);

    if (k0 <= qw + 31) {
      f32x4 sT[2][4] = {};
      __builtin_amdgcn_s_setprio(1);
#pragma unroll
      for (int p = 0; p < 4; ++p) {
        const int lrow = p * 16 + l15;
#pragma unroll
        for (int s = 0; s < 4; ++s) {
          const int lbyte = (lrow << 8) + ((s * 64 + l4 * 16) ^ ((lrow & 7) << 4));
          const bf16x8 kf = *(const bf16x8*)((const char*)&Ks[cur][0] + lbyte);
          sT[0][p] = __builtin_amdgcn_mfma_f32_16x16x32_bf16(kf, qf[0][s], sT[0][p], 0, 0, 0);
          sT[1][p] = __builtin_amdgcn_mfma_f32_16x16x32_bf16(kf, qf[1][s], sT[1][p], 0, 0, 0);
        }
      }
      __builtin_amdgcn_s_setprio(0);

      const short* vp = vbase + (size_t)l15 * NS + k0 + l4 * 8;
      bf16x8 vA[8];
#pragma unroll
      for (int t8 = 0; t8 < 8; ++t8)
        vA[t8] = *(const bf16x8*)(vp + (size_t)t8 * 16 * NS);

      const bool full = (k0 + 63 <= qw);
      float pv[2][16];
      float tmax[2] = {-1e30f, -1e30f};
#pragma unroll
      for (int p = 0; p < 4; ++p) {
        const f32x4 bvec = *(const f32x4*)&biasLds[k0 + p * 16 + l4 * 4];
#pragma unroll
        for (int r = 0; r < 4; ++r) {
          const int kg = k0 + p * 16 + l4 * 4 + r;
          float v0 = sT[0][p][r] + bvec[r];
          float v1 = sT[1][p][r] + bvec[r];
          if (!full) {
            v0 = (kg <= qg0) ? v0 : -1e30f;
            v1 = (kg <= qg1) ? v1 : -1e30f;
          }
          pv[0][p * 4 + r] = v0; pv[1][p * 4 + r] = v1;
          tmax[0] = fmaxf(tmax[0], v0);
          tmax[1] = fmaxf(tmax[1], v1);
        }
      }
#pragma unroll
      for (int c = 0; c < 2; ++c) {
        tmax[c] = fmaxf(tmax[c], __shfl_xor(tmax[c], 16, 64));
        tmax[c] = fmaxf(tmax[c], __shfl_xor(tmax[c], 32, 64));
        if (tmax[c] > mrun[c] + 8.0f) {       // T13 defer-max
          const float mnew = tmax[c];
          const float alpha = __expf(mrun[c] - mnew);
          mrun[c] = mnew;
          lrun[c] *= alpha;
#pragma unroll
          for (int t8 = 0; t8 < 8; ++t8)
#pragma unroll
            for (int r = 0; r < 4; ++r)
              acc[c][t8][r] *= alpha;
        }
        float psum = 0.f;
#pragma unroll
        for (int i = 0; i < 16; ++i) {
          pv[c][i] = __expf(pv[c][i] - mrun[c]);
          psum += pv[c][i];
        }
        psum += __shfl_xor(psum, 16, 64);
        psum += __shfl_xor(psum, 32, 64);
        lrun[c] += psum;
      }

#pragma unroll
      for (int c = 0; c < 2; ++c)
#pragma unroll
        for (int p = 0; p < 4; ++p) {
          bf16x4 pk = { (__bf16)pv[c][p * 4 + 0], (__bf16)pv[c][p * 4 + 1],
                        (__bf16)pv[c][p * 4 + 2], (__bf16)pv[c][p * 4 + 3] };
          const int byteoff = ((16 * c + l15) << 7) + (((p * 16 + l4 * 4) << 1) ^ pswzB);
          *(bf16x4*)((char*)myP + byteoff) = pk;
        }
      asm volatile("s_waitcnt lgkmcnt(0)" ::: "memory");

      bf16x8 pfA[2], pfB[2];
#pragma unroll
      for (int c = 0; c < 2; ++c)
        pfA[c] = *(const bf16x8*)((const char*)myP + ((16 * c + l15) << 7) + ((l4 * 16) ^ pswzB));
      bf16x8 vB[8];
#pragma unroll
      for (int t8 = 0; t8 < 8; ++t8)
        vB[t8] = *(const bf16x8*)(vp + 32 + (size_t)t8 * 16 * NS);
      __builtin_amdgcn_s_setprio(1);
#pragma unroll
      for (int t8 = 0; t8 < 8; ++t8) {
        acc[0][t8] = __builtin_amdgcn_mfma_f32_16x16x32_bf16(vA[t8], pfA[0], acc[0][t8], 0, 0, 0);
        acc[1][t8] = __builtin_amdgcn_mfma_f32_16x16x32_bf16(vA[t8], pfA[1], acc[1][t8], 0, 0, 0);
      }
      __builtin_amdgcn_s_setprio(0);
#pragma unroll
      for (int c = 0; c < 2; ++c)
        pfB[c] = *(const bf16x8*)((const char*)myP + ((16 * c + l15) << 7) + ((64 + l4 * 16) ^ pswzB));
      __builtin_amdgcn_s_setprio(1);
#pragma unroll
      for (int t8 = 0; t8 < 8; ++t8) {
        acc[0][t8] = __builtin_amdgcn_mfma_f32_16x16x32_bf16(vB[t8], pfB[0], acc[0][t8], 0, 0, 0);
        acc[1][t8] = __builtin_amdgcn_mfma_f32_16x16x32_bf16(vB[t8], pfB[1], acc[1][t8], 0, 0, 0);
      }
      __builtin_amdgcn_s_setprio(0);
    }

    __syncthreads();
    cur ^= 1;
  }
#undef KSTAGE

#pragma unroll
  for (int c = 0; c < 2; ++c) {
    const float inv = (lrun[c] > 0.f) ? 1.0f / lrun[c] : 0.f;
    short* obase = Ob + ((size_t)bb * NS + qw + 16 * c + l15) * ND + h * NHD + l4 * 4;
#pragma unroll
    for (int t8 = 0; t8 < 8; ++t8) {
      bf16x4 o = { (__bf16)(acc[c][t8][0] * inv), (__bf16)(acc[c][t8][1] * inv),
                   (__bf16)(acc[c][t8][2] * inv), (__bf16)(acc[c][t8][3] * inv) };
      *(bf16x4*)&obase[t8 * 16] = o;
    }
  }
}

extern "C" void kernel_launch(void* const* d_in, const int* in_sizes, int n_in,
                              void* d_out, int out_size, void* d_ws, size_t ws_size,
                              hipStream_t stream) {
  const float* hidden   = (const float*)d_in[0];
  const float* residual = (const float*)d_in[1];
  const float* alibi    = (const float*)d_in[2];
  const float* W_qkv    = (const float*)d_in[3];
  const float* b_qkv    = (const float*)d_in[4];
  const float* W_o      = (const float*)d_in[5];
  const float* b_o      = (const float*)d_in[6];
  const int*   amask    = (const int*)d_in[7];
  float* out = (float*)d_out;

  char* p = (char*)d_ws;
  short* Abuf  = (short*)p; p += (size_t)NM * ND * 2;
  short* WqkvT = (short*)p; p += (size_t)NQKV * ND * 2;
  short* WoT   = (short*)p; p += (size_t)ND * ND * 2;
  short* Qb    = (short*)p; p += (size_t)NB * NH * NS * NHD * 2;
  short* Kb    = (short*)p; p += (size_t)NB * NH * NS * NHD * 2;
  short* Vtb   = (short*)p; p += (size_t)NB * NH * NS * NHD * 2;
  short* Ob    = (short*)p; p += (size_t)NM * ND * 2;

  prep_kernel<<<dim3(12288), 256, 0, stream>>>(hidden, Abuf, W_qkv, WqkvT, W_o, WoT);
  gemm_kernel<0><<<dim3((NM / 128) * (NQKV / 128)), 256, 0, stream>>>(
      Abuf, WqkvT, ND, NQKV, NQKV / 128, b_qkv, Qb, Kb, Vtb, nullptr, nullptr);
  attn_kernel<<<dim3(512), 256, 0, stream>>>(Qb, Kb, Vtb, alibi, amask, Ob);
  gemm_kernel<1><<<dim3((NM / 128) * (ND / 128)), 256, 0, stream>>>(
      Ob, WoT, ND, ND, ND / 128, b_o, nullptr, nullptr, nullptr, residual, out);
}

// Round 19
// 299.050 us; speedup vs baseline: 1.4593x; 1.4593x over previous
//
#include <hip/hip_runtime.h>
#include <stdint.h>

typedef __attribute__((ext_vector_type(4))) float f32x4;
typedef __attribute__((ext_vector_type(8))) __bf16 bf16x8;
typedef __attribute__((ext_vector_type(4))) __bf16 bf16x4;

#define NB 2
#define NS 2048
#define ND 2048
#define NH 16
#define NHD 128
#define NM (NB*NS)      // 4096 rows
#define NQKV (3*ND)     // 6144

__device__ __forceinline__ short f2bf(float f) {
  union { float f; uint32_t u; } c; c.f = f;
  uint32_t r = (c.u + 0x7FFFu + ((c.u >> 16) & 1u)) >> 16;
  return (short)r;
}

__device__ __forceinline__ void gl_lds16(const short* g, short* l) {
  __builtin_amdgcn_global_load_lds(
      (const __attribute__((address_space(1))) void*)g,
      (__attribute__((address_space(3))) void*)l, 16, 0, 0);
}

// ---------------- fused prepass: cvt hidden + transpose W_qkv + transpose W_o ----
__global__ __launch_bounds__(256) void prep_kernel(
    const float* __restrict__ hidden, short* __restrict__ Abuf,
    const float* __restrict__ W_qkv, short* __restrict__ WqkvT,
    const float* __restrict__ W_o, short* __restrict__ WoT) {
  __shared__ float tile[64][65];
  const int b = blockIdx.x;
  if (b < 8192) {
    const int i = b * 256 + threadIdx.x;
    float4 v = ((const float4*)hidden)[i];
    short4 o;
    o.x = f2bf(v.x); o.y = f2bf(v.y); o.z = f2bf(v.z); o.w = f2bf(v.w);
    ((short4*)Abuf)[i] = o;
  } else {
    const float* in; short* out; int cols, t;
    if (b < 11264) { in = W_qkv; out = WqkvT; cols = NQKV; t = b - 8192; }
    else           { in = W_o;   out = WoT;   cols = ND;   t = b - 11264; }
    const int rows = ND;
    const int nbx = cols >> 6;
    const int bx = t % nbx, by = t / nbx;
    const int tx = threadIdx.x & 63, ty = threadIdx.x >> 6;
    const int r0 = by * 64, c0 = bx * 64;
    for (int i = ty; i < 64; i += 4)
      tile[i][tx] = in[(size_t)(r0 + i) * cols + c0 + tx];
    __syncthreads();
    for (int i = ty; i < 64; i += 4)
      out[(size_t)(c0 + i) * rows + r0 + tx] = f2bf(tile[tx][i]);
  }
}

// ---------------- bf16 GEMM, BM=128 x BN=64*NFH, BK=64, 4 waves (2x2) ----------------
// r16 structure (race-free: lgkmcnt(0) before EVERY barrier; counted vmcnt(4) at
// P0-end leaves exactly A(t+2) in flight). r18: BN templated — QKV uses NFH=3
// (BN=192, LDS 80KB, still 2 blocks/CU) to cut staging traffic/FLOP by 20%
// (traffic ~ 1/BM + 1/BN; step-time model shows L2-staging co-bound at 1838cy).
// O-proj keeps NFH=2 (= r16 bit-identical). Per-element accumulation order
// unchanged -> output bitwise identical to r16 (absmax must stay 0.03125).
template<int EPI, int NFH>   // NFH = B n-fragments per half; BN = 64*NFH
__global__ __launch_bounds__(256, 2) void gemm_kernel(
    const short* __restrict__ A, const short* __restrict__ Bt, int K, int N, int nbx,
    const float* __restrict__ bias,
    short* __restrict__ Qb, short* __restrict__ Kb, short* __restrict__ Vtb,
    const float* __restrict__ residual, float* __restrict__ out) {
  constexpr int BN = 64 * NFH;
  constexpr int NBC = 2 * NFH;            // B chunks (32 rows each)
  const int tid = threadIdx.x;
  const int wid = tid >> 6, l = tid & 63;
  const int l15 = l & 15, l4 = l >> 4;
  const int wr = wid >> 1, wc = wid & 1;

  // 2D XCD chunking: xcd = flat & 7; by fastest -> per-XCD B slice L2-resident
  const int flat = blockIdx.x;
  const int xcd = flat & 7;
  const int j = flat >> 3;
  const int nchunk = nbx >> 3;
  const int bx = nchunk * xcd + (j >> 5);
  const int by = j & 31;                  // NM/128 = 32 row-panels
  const int rowBase = by * 128, colBase = bx * BN;

  __shared__ short As[2][128 * 64];       // 32 KB
  __shared__ short Bs[2][BN * 64];        // NFH=2: 32 KB, NFH=3: 48 KB

  f32x4 acc[4][NBC] = {};
  const int nk = K >> 6;

  const int crow = tid >> 3;
  const int scol = ((tid & 7) ^ ((tid >> 3) & 7)) << 3;

#define STGC(ldsArr, buf, ci, gptr, gbase)                                       \
    gl_lds16((gptr) + (size_t)((gbase) + (ci) * 32 + crow) * K + kOff_,          \
             &(ldsArr)[buf][((ci) * 32 + wid * 8) * 64])
#define STG_A(buf, kt0) do { const size_t kOff_ = (size_t)(kt0) * 64 + scol;     \
    STGC(As, buf, 0, A, rowBase); STGC(As, buf, 1, A, rowBase);                  \
    STGC(As, buf, 2, A, rowBase); STGC(As, buf, 3, A, rowBase); } while (0)
#define STG_B(buf, kt0) do { const size_t kOff_ = (size_t)(kt0) * 64 + scol;     \
    _Pragma("unroll")                                                            \
    for (int ci_ = 0; ci_ < NBC; ++ci_) STGC(Bs, buf, ci_, Bt, colBase); } while (0)

  bf16x8 afS0[4][2], afS1[4][2], bfLo[NFH][2], bfHi[NFH][2];
  const int aXor = (l15 & 7) << 4;
  const int aColB = l4 * 16;

#define LDA(buf, DST)                                                            \
  _Pragma("unroll")                                                              \
  for (int m_ = 0; m_ < 4; ++m_) {                                               \
    const int r_ = wr * 64 + m_ * 16 + l15;                                      \
    _Pragma("unroll")                                                            \
    for (int kk_ = 0; kk_ < 2; ++kk_)                                            \
      DST[m_][kk_] = *(const bf16x8*)((const char*)&As[buf][0] + r_ * 128 +      \
                                      ((kk_ * 64 + aColB) ^ aXor));              \
  }
#define LDBn(buf, DST, nb)                                                       \
  _Pragma("unroll")                                                              \
  for (int n_ = 0; n_ < NFH; ++n_) {                                             \
    const int r_ = wc * (32 * NFH) + ((nb) + n_) * 16 + l15;                     \
    _Pragma("unroll")                                                            \
    for (int kk_ = 0; kk_ < 2; ++kk_)                                            \
      DST[n_][kk_] = *(const bf16x8*)((const char*)&Bs[buf][0] + r_ * 128 +      \
                                      ((kk_ * 64 + aColB) ^ aXor));              \
  }
#define MMAQ(AF, BF, nb)                                                         \
  _Pragma("unroll")                                                              \
  for (int m_ = 0; m_ < 4; ++m_)                                                 \
    _Pragma("unroll")                                                            \
    for (int n_ = 0; n_ < NFH; ++n_)                                             \
      _Pragma("unroll")                                                          \
      for (int kk_ = 0; kk_ < 2; ++kk_)                                          \
        acc[m_][(nb) + n_] = __builtin_amdgcn_mfma_f32_16x16x32_bf16(            \
            AF[m_][kk_], BF[n_][kk_], acc[m_][(nb) + n_], 0, 0, 0);

  // P0: stage A(t+2) (safe: all LDS reads drained at entry barrier); read
  //     bfHi(cur); MMA half0; lgkm(0); vmcnt(4) [retires A(t+1)+B(t+1), leaves
  //     A(t+2) by FIFO]; barrier.
  // P1: stage B(t+2) (safe: bfHi drained by all at P0 barrier); read A(t+1)+
  //     bfLo(t+1) from other buf; MMA half1; lgkm(0); barrier.
#define TILE(kt, AFc, AFn, cur)                                                  \
  do {                                                                           \
    const bool stA = (kt) + 2 < nk;                                              \
    const bool nxt = (kt) + 1 < nk;                                              \
    if (stA) STG_A(cur, (kt) + 2);                                               \
    LDBn(cur, bfHi, NFH);                                                        \
    __builtin_amdgcn_sched_barrier(0);                                           \
    __builtin_amdgcn_s_setprio(1);                                               \
    MMAQ(AFc, bfLo, 0);                                                          \
    __builtin_amdgcn_s_setprio(0);                                               \
    __builtin_amdgcn_sched_barrier(0);                                           \
    asm volatile("s_waitcnt lgkmcnt(0)" ::: "memory");                           \
    if (stA)      { asm volatile("s_waitcnt vmcnt(4)" ::: "memory"); }           \
    else if (nxt) { asm volatile("s_waitcnt vmcnt(0)" ::: "memory"); }           \
    __builtin_amdgcn_s_barrier();                                                \
    if (stA) STG_B(cur, (kt) + 2);                                               \
    if (nxt) { LDA(cur ^ 1, AFn); LDBn(cur ^ 1, bfLo, 0); }                      \
    __builtin_amdgcn_sched_barrier(0);                                           \
    __builtin_amdgcn_s_setprio(1);                                               \
    MMAQ(AFc, bfHi, NFH);                                                        \
    __builtin_amdgcn_s_setprio(0);                                               \
    __builtin_amdgcn_sched_barrier(0);                                           \
    asm volatile("s_waitcnt lgkmcnt(0)" ::: "memory");                           \
    __builtin_amdgcn_s_barrier();                                                \
  } while (0)

  // prologue: prime tiles 0,1; wait tile 0 (tile-1's 4+NBC stay in flight);
  // tile-0 fragment reads drained + barrier before loop (TILE(0) stages As[0]).
  STG_A(0, 0); STG_B(0, 0);
  STG_A(1, 1); STG_B(1, 1);
  if constexpr (NFH == 2) { asm volatile("s_waitcnt vmcnt(8)"  ::: "memory"); }
  else                    { asm volatile("s_waitcnt vmcnt(10)" ::: "memory"); }
  __builtin_amdgcn_s_barrier();
  LDA(0, afS0); LDBn(0, bfLo, 0);
  asm volatile("s_waitcnt lgkmcnt(0)" ::: "memory");
  __builtin_amdgcn_s_barrier();

  for (int kt = 0; kt < nk; kt += 2) {
    TILE(kt,     afS0, afS1, 0);
    TILE(kt + 1, afS1, afS0, 1);
  }
#undef STGC
#undef STG_A
#undef STG_B
#undef LDA
#undef LDBn
#undef MMAQ
#undef TILE

#pragma unroll
  for (int m = 0; m < 4; ++m) {
#pragma unroll
    for (int n = 0; n < NBC; ++n) {
#pragma unroll
      for (int r = 0; r < 4; ++r) {
        const int row = rowBase + wr * 64 + m * 16 + l4 * 4 + r;
        const int col = colBase + wc * (32 * NFH) + n * 16 + l15;
        float v = acc[m][n][r] + bias[col];
        if (EPI == 0) {
          const int h = col / 384;
          const int sub = col - h * 384;
          const int t = sub >> 7, hd = sub & 127;
          const int bb = row >> 11, s = row & 2047;
          const size_t bh = (size_t)bb * NH + h;
          if (t == 0)      Qb[(bh * NS + s) * NHD + hd] = f2bf(v * 0.08838834764831845f);
          else if (t == 1) Kb[(bh * NS + s) * NHD + hd] = f2bf(v);
          else             Vtb[(bh * NHD + hd) * NS + s] = f2bf(v);
        } else {
          const size_t idx = (size_t)row * N + col;
          out[idx] = v + residual[idx];
        }
      }
    }
  }
}

// ---------------- flash attention (r11/r16 known-good, byte-identical) ----------------
__global__ __launch_bounds__(256, 2) void attn_kernel(
    const short* __restrict__ Qb, const short* __restrict__ Kb,
    const short* __restrict__ Vtb, const float* __restrict__ alibi,
    const int* __restrict__ amask, short* __restrict__ Ob) {
  const int tid = threadIdx.x;
  const int w = tid >> 6, l = tid & 63;
  const int l15 = l & 15, l4 = l >> 4;
  const int flat = blockIdx.x;
  const int bh = flat & 31;
  const int y = (flat >> 5) & 7, z = flat >> 8;
  const int qt = z ? (15 - y) : y;
  const int bb = bh >> 4, h = bh & 15;
  const int q0 = qt * 128;
  const int qw = q0 + w * 32;
  const int NT = 2 * qt + 2;

  __shared__ float biasLds[NS];
  __shared__ short Ks[2][64 * 128];
  __shared__ short Plds[4][32 * 64];

  {
    const float* abase = alibi + (size_t)bh * NS;
    const int* mbase = amask + (size_t)bb * NS;
    for (int i = tid; i < NS; i += 256)
      biasLds[i] = mbase[i] ? abase[i] : -1e30f;
  }

  const short* kbase = Kb + (size_t)bh * NS * NHD;
  const short* vbase = Vtb + (size_t)bh * NHD * NS;

#define KSTAGE(buf, kt0) do {                                                  \
    _Pragma("unroll")                                                          \
    for (int i_ = 0; i_ < 4; ++i_) {                                           \
      const int Lb_ = w * 4096 + i_ * 1024 + l * 16;                           \
      const int row_ = Lb_ >> 8;                                               \
      const int X_ = (Lb_ & 255) ^ ((row_ & 7) << 4);                          \
      gl_lds16((const short*)((const char*)kbase + (size_t)((kt0) * 64 + row_) * 256 + X_), \
               (short*)((char*)&Ks[buf][0] + (w * 4096 + i_ * 1024)));         \
    }                                                                          \
  } while (0)

  const short* qp = Qb + ((size_t)bh * NS + qw + l15) * NHD + l4 * 8;
  bf16x8 qf[2][4];
#pragma unroll
  for (int c = 0; c < 2; ++c)
#pragma unroll
    for (int s = 0; s < 4; ++s)
      qf[c][s] = *(const bf16x8*)(qp + c * 16 * NHD + s * 32);

  f32x4 acc[2][8] = {};
  float mrun[2] = {-1e30f, -1e30f}, lrun[2] = {0.f, 0.f};

  short* myP = &Plds[w][0];
  const int pswzB = (l15 & 7) << 4;
  const int qg0 = qw + l15, qg1 = qw + 16 + l15;

  KSTAGE(0, 0);
  __syncthreads();
  int cur = 0;

  for (int t = 0; t < NT; ++t) {
    const int k0 = t << 6;
    if (t + 1 < NT) KSTAGE(cur ^ 1, t + 1);

    if (k0 <= qw + 31) {
      f32x4 sT[2][4] = {};
      __builtin_amdgcn_s_setprio(1);
#pragma unroll
      for (int p = 0; p < 4; ++p) {
        const int lrow = p * 16 + l15;
#pragma unroll
        for (int s = 0; s < 4; ++s) {
          const int lbyte = (lrow << 8) + ((s * 64 + l4 * 16) ^ ((lrow & 7) << 4));
          const bf16x8 kf = *(const bf16x8*)((const char*)&Ks[cur][0] + lbyte);
          sT[0][p] = __builtin_amdgcn_mfma_f32_16x16x32_bf16(kf, qf[0][s], sT[0][p], 0, 0, 0);
          sT[1][p] = __builtin_amdgcn_mfma_f32_16x16x32_bf16(kf, qf[1][s], sT[1][p], 0, 0, 0);
        }
      }
      __builtin_amdgcn_s_setprio(0);

      const short* vp = vbase + (size_t)l15 * NS + k0 + l4 * 8;
      bf16x8 vA[8];
#pragma unroll
      for (int t8 = 0; t8 < 8; ++t8)
        vA[t8] = *(const bf16x8*)(vp + (size_t)t8 * 16 * NS);

      const bool full = (k0 + 63 <= qw);
      float pv[2][16];
      float tmax[2] = {-1e30f, -1e30f};
#pragma unroll
      for (int p = 0; p < 4; ++p) {
        const f32x4 bvec = *(const f32x4*)&biasLds[k0 + p * 16 + l4 * 4];
#pragma unroll
        for (int r = 0; r < 4; ++r) {
          const int kg = k0 + p * 16 + l4 * 4 + r;
          float v0 = sT[0][p][r] + bvec[r];
          float v1 = sT[1][p][r] + bvec[r];
          if (!full) {
            v0 = (kg <= qg0) ? v0 : -1e30f;
            v1 = (kg <= qg1) ? v1 : -1e30f;
          }
          pv[0][p * 4 + r] = v0; pv[1][p * 4 + r] = v1;
          tmax[0] = fmaxf(tmax[0], v0);
          tmax[1] = fmaxf(tmax[1], v1);
        }
      }
#pragma unroll
      for (int c = 0; c < 2; ++c) {
        tmax[c] = fmaxf(tmax[c], __shfl_xor(tmax[c], 16, 64));
        tmax[c] = fmaxf(tmax[c], __shfl_xor(tmax[c], 32, 64));
        if (tmax[c] > mrun[c] + 8.0f) {       // T13 defer-max
          const float mnew = tmax[c];
          const float alpha = __expf(mrun[c] - mnew);
          mrun[c] = mnew;
          lrun[c] *= alpha;
#pragma unroll
          for (int t8 = 0; t8 < 8; ++t8)
#pragma unroll
            for (int r = 0; r < 4; ++r)
              acc[c][t8][r] *= alpha;
        }
        float psum = 0.f;
#pragma unroll
        for (int i = 0; i < 16; ++i) {
          pv[c][i] = __expf(pv[c][i] - mrun[c]);
          psum += pv[c][i];
        }
        psum += __shfl_xor(psum, 16, 64);
        psum += __shfl_xor(psum, 32, 64);
        lrun[c] += psum;
      }

#pragma unroll
      for (int c = 0; c < 2; ++c)
#pragma unroll
        for (int p = 0; p < 4; ++p) {
          bf16x4 pk = { (__bf16)pv[c][p * 4 + 0], (__bf16)pv[c][p * 4 + 1],
                        (__bf16)pv[c][p * 4 + 2], (__bf16)pv[c][p * 4 + 3] };
          const int byteoff = ((16 * c + l15) << 7) + (((p * 16 + l4 * 4) << 1) ^ pswzB);
          *(bf16x4*)((char*)myP + byteoff) = pk;
        }
      asm volatile("s_waitcnt lgkmcnt(0)" ::: "memory");

      bf16x8 pfA[2], pfB[2];
#pragma unroll
      for (int c = 0; c < 2; ++c)
        pfA[c] = *(const bf16x8*)((const char*)myP + ((16 * c + l15) << 7) + ((l4 * 16) ^ pswzB));
      bf16x8 vB[8];
#pragma unroll
      for (int t8 = 0; t8 < 8; ++t8)
        vB[t8] = *(const bf16x8*)(vp + 32 + (size_t)t8 * 16 * NS);
      __builtin_amdgcn_s_setprio(1);
#pragma unroll
      for (int t8 = 0; t8 < 8; ++t8) {
        acc[0][t8] = __builtin_amdgcn_mfma_f32_16x16x32_bf16(vA[t8], pfA[0], acc[0][t8], 0, 0, 0);
        acc[1][t8] = __builtin_amdgcn_mfma_f32_16x16x32_bf16(vA[t8], pfA[1], acc[1][t8], 0, 0, 0);
      }
      __builtin_amdgcn_s_setprio(0);
#pragma unroll
      for (int c = 0; c < 2; ++c)
        pfB[c] = *(const bf16x8*)((const char*)myP + ((16 * c + l15) << 7) + ((64 + l4 * 16) ^ pswzB));
      __builtin_amdgcn_s_setprio(1);
#pragma unroll
      for (int t8 = 0; t8 < 8; ++t8) {
        acc[0][t8] = __builtin_amdgcn_mfma_f32_16x16x32_bf16(vB[t8], pfB[0], acc[0][t8], 0, 0, 0);
        acc[1][t8] = __builtin_amdgcn_mfma_f32_16x16x32_bf16(vB[t8], pfB[1], acc[1][t8], 0, 0, 0);
      }
      __builtin_amdgcn_s_setprio(0);
    }

    __syncthreads();
    cur ^= 1;
  }
#undef KSTAGE

#pragma unroll
  for (int c = 0; c < 2; ++c) {
    const float inv = (lrun[c] > 0.f) ? 1.0f / lrun[c] : 0.f;
    short* obase = Ob + ((size_t)bb * NS + qw + 16 * c + l15) * ND + h * NHD + l4 * 4;
#pragma unroll
    for (int t8 = 0; t8 < 8; ++t8) {
      bf16x4 o = { (__bf16)(acc[c][t8][0] * inv), (__bf16)(acc[c][t8][1] * inv),
                   (__bf16)(acc[c][t8][2] * inv), (__bf16)(acc[c][t8][3] * inv) };
      *(bf16x4*)&obase[t8 * 16] = o;
    }
  }
}

extern "C" void kernel_launch(void* const* d_in, const int* in_sizes, int n_in,
                              void* d_out, int out_size, void* d_ws, size_t ws_size,
                              hipStream_t stream) {
  const float* hidden   = (const float*)d_in[0];
  const float* residual = (const float*)d_in[1];
  const float* alibi    = (const float*)d_in[2];
  const float* W_qkv    = (const float*)d_in[3];
  const float* b_qkv    = (const float*)d_in[4];
  const float* W_o      = (const float*)d_in[5];
  const float* b_o      = (const float*)d_in[6];
  const int*   amask    = (const int*)d_in[7];
  float* out = (float*)d_out;

  char* p = (char*)d_ws;
  short* Abuf  = (short*)p; p += (size_t)NM * ND * 2;
  short* WqkvT = (short*)p; p += (size_t)NQKV * ND * 2;
  short* WoT   = (short*)p; p += (size_t)ND * ND * 2;
  short* Qb    = (short*)p; p += (size_t)NB * NH * NS * NHD * 2;
  short* Kb    = (short*)p; p += (size_t)NB * NH * NS * NHD * 2;
  short* Vtb   = (short*)p; p += (size_t)NB * NH * NS * NHD * 2;
  short* Ob    = (short*)p; p += (size_t)NM * ND * 2;

  prep_kernel<<<dim3(12288), 256, 0, stream>>>(hidden, Abuf, W_qkv, WqkvT, W_o, WoT);
  // QKV: BN=192 (NFH=3), grid 32*32 = 1024 (%8==0), 2 exact passes, 2 blocks/CU
  gemm_kernel<0, 3><<<dim3((NM / 128) * (NQKV / 192)), 256, 0, stream>>>(
      Abuf, WqkvT, ND, NQKV, NQKV / 192, b_qkv, Qb, Kb, Vtb, nullptr, nullptr);
  attn_kernel<<<dim3(512), 256, 0, stream>>>(Qb, Kb, Vtb, alibi, amask, Ob);
  // O-proj: BN=128 (NFH=2) — r16 bit-identical
  gemm_kernel<1, 2><<<dim3((NM / 128) * (ND / 128)), 256, 0, stream>>>(
      Ob, WoT, ND, ND, ND / 128, b_o, nullptr, nullptr, nullptr, residual, out);
}